// Round 15
// baseline (1043.161 us; speedup 1.0000x reference)
//
#include <hip/hip_runtime.h>
#include <hip/hip_bf16.h>

typedef __attribute__((ext_vector_type(8))) short short8;
typedef __attribute__((ext_vector_type(4))) float f32x4;
typedef __attribute__((ext_vector_type(4))) unsigned u32x4;
typedef unsigned short u16;

// Problem constants
#define BB 512     // batch
#define HH 1024    // hidden
#define TT 25      // decoder steps
#define CTB 128    // ct slices (each owns 8 hidden cols -> 48 Wc rows)
#define HSZ (BB*HH)   // elements in one h_bf buffer

// h_bf layout (A-frag tiled, per buffer): u16 index of (b, j) =
//   ((b>>4)*32 + (j>>5))*512 + (b&15)*32 + (j&31)

__device__ __forceinline__ float sigm(float x){ return 1.f/(1.f+__expf(-x)); }
__device__ __forceinline__ float tanh_(float x){
  float e = __expf(-2.f*fabsf(x));
  float t = (1.f-e)/(1.f+e);
  return copysignf(t, x);
}
__device__ __forceinline__ u16 f2bf(float x){
  union { float f; unsigned u; } v; v.f = x;
  unsigned r = v.u + 0x7FFFu + ((v.u>>16)&1u);
  return (u16)(r>>16);
}
// 16B write-through store (visible at coherence point after vmcnt drain)
__device__ __forceinline__ void store16_wt(void* p, u32x4 v){
  asm volatile("global_store_dwordx4 %0, %1, off sc0 sc1" :: "v"(p), "v"(v) : "memory");
}
// un-sinkable 16B load into explicit VGPRs (completion via manual s_waitcnt)
__device__ __forceinline__ void aload(short8 &d, const short8* p){
  asm volatile("global_load_dwordx4 %0, %1, off" : "=v"(d) : "v"(p));
}

#if __has_builtin(__builtin_amdgcn_global_load_lds)
#define GLOAD_LDS16(g, l) __builtin_amdgcn_global_load_lds( \
    (const __attribute__((address_space(1))) void*)(g), \
    (__attribute__((address_space(3))) void*)(l), 16, 0, 0)
#define HAVE_GLL 1
#else
#define HAVE_GLL 0
#endif

// Wcp layout: per ct slice (8 hidden cols), 48 rows (r = gate*8 + u, gates:
// 0=gir 1=giz 2=gin 3=ghr 4=ghz 5=ghn), pre-packed in MFMA B-frag order:
// elem idx = ct*49152 + ((kit*3 + nf)*64 + lane)*8 + e
__device__ __forceinline__ size_t wc_idx(int ct, int r, int k){
  int nf = r>>4, rl = r&15, kit = k>>5, k31 = k&31;
  int lane = rl | (((k31>>3)&3)<<4);
  return (size_t)ct*49152 + ((size_t)(kit*3+nf)*64 + (size_t)lane)*8 + (k31&7);
}

// ================= merged prep kernel (one launch) =================
// blocks [0,1536): wx | [1536,4704): cast | [4704,4716): cx | [4716,4844): step0

__device__ void prep_wx_body(int bid, float* smem,
                             const float* __restrict__ Wih,
                             const float* __restrict__ Wout,
                             u16* __restrict__ Wcp){
  float (*sWih)[97] = (float(*)[97])smem;            // 32*97
  float (*sWo)[97]  = (float(*)[97])(smem + 32*97);  // 64*97
  int tid = threadIdx.x;
  int nt = bid % 96, kt = bid / 96;   // n-tile 32, k-tile 64
  for (int i = tid; i < 32*96; i += 256){ int r2=i/96, d=i%96; sWih[r2][d] = Wih[(size_t)(nt*32+r2)*96 + d]; }
  for (int i = tid; i < 64*96; i += 256){ int r2=i/96, d=i%96; sWo[r2][d]  = Wout[(size_t)(kt*64+r2)*96 + d]; }
  __syncthreads();
  int ni = tid & 31, kb = tid >> 5;    // thread owns 8 consecutive k
  float acc[8];
  #pragma unroll
  for (int i=0;i<8;i++) acc[i]=0.f;
  for (int d = 0; d < 96; d++){
    float a = sWih[ni][d];
    #pragma unroll
    for (int i=0;i<8;i++) acc[i] += a * sWo[kb*8 + i][d];
  }
  int n = nt*32 + ni;
  int g = n >> 10, j = n & 1023;
  int ct = j >> 3, u = j & 7, r = g*8 + u;
  size_t base = wc_idx(ct, r, kt*64 + kb*8);
  #pragma unroll
  for (int i=0;i<8;i++) Wcp[base+i] = f2bf(acc[i]);
}

__device__ void prep_cast_body(int bid,
                               const float* __restrict__ Whh, const float* __restrict__ bhh,
                               const float* __restrict__ Wout,
                               u16* __restrict__ Wcp, float* __restrict__ cbias,
                               u16* __restrict__ WoT){
  int tid = threadIdx.x;
  if (bid < 3072){
    int g1 = bid >> 10, j = bid & 1023;
    int ct = j >> 3, u = j & 7, r = (3+g1)*8 + u;
    const float* src = Whh + (size_t)bid*1024;
    if (tid < 128){
      int k0 = tid*8;
      size_t base = wc_idx(ct, r, k0);
      #pragma unroll
      for (int i=0;i<8;i++) Wcp[base+i] = f2bf(src[k0+i]);
    }
    if (!tid) cbias[ct*48 + r] = bhh[bid];
  } else {
    int d = bid - 3072;
    for (int k = tid; k < 1024; k += 256)
      WoT[(size_t)d*1024 + k] = f2bf(Wout[(size_t)k*96 + d]);
  }
}

__device__ void prep_cx_body(int bid,
                             const float* __restrict__ Wih, const float* __restrict__ bih,
                             const float* __restrict__ bout, float* __restrict__ cbias){
  int n = bid*256 + threadIdx.x;
  if (n >= 3072) return;
  float acc = bih[n];
  const float* wrow = Wih + (size_t)n*96;
  for (int d = 0; d < 96; d++) acc += bout[d]*wrow[d];
  int g = n >> 10, j = n & 1023;
  cbias[(j>>3)*48 + g*8 + (j&7)] = acc;
}

__device__ void step0_body(int bid, float* smem,
                           const float* __restrict__ dec_in, const float* __restrict__ Wih,
                           const float* __restrict__ bih, const float* __restrict__ bhh,
                           float* __restrict__ h_f32, u16* __restrict__ h_bf,
                           unsigned* __restrict__ flags){
  if (bid == 0 && threadIdx.x < 256) flags[threadIdx.x] = 0u;
  float (*sP)[97] = (float(*)[97])smem;            // 64*97
  float (*sW)[97] = (float(*)[97])(smem + 64*97);  // 64*97
  int tid = threadIdx.x;
  int bt = bid & 7;
  int jt = bid >> 3;
  for (int i = tid; i < 64*96; i += 256){ int r=i/96, d=i%96; sP[r][d] = dec_in[(size_t)(bt*64+r)*96 + d]; }
  int tb = tid >> 4, tj = tid & 15;
  float gg[3][4][4];
  for (int g = 0; g < 3; g++){
    __syncthreads();
    for (int i = tid; i < 64*96; i += 256){ int r=i/96, d=i%96; sW[r][d] = Wih[((size_t)g*1024 + jt*64 + r)*96 + d]; }
    __syncthreads();
    float acc[4][4];
    #pragma unroll
    for (int x=0;x<4;x++)
      #pragma unroll
      for (int y=0;y<4;y++) acc[x][y]=0.f;
    for (int d = 0; d < 96; d++){
      float a[4], wv[4];
      #pragma unroll
      for (int x=0;x<4;x++) a[x]  = sP[tb + x*16][d];
      #pragma unroll
      for (int y=0;y<4;y++) wv[y] = sW[tj + y*16][d];
      #pragma unroll
      for (int x=0;x<4;x++)
        #pragma unroll
        for (int y=0;y<4;y++) acc[x][y] += a[x]*wv[y];
    }
    #pragma unroll
    for (int x=0;x<4;x++)
      #pragma unroll
      for (int y=0;y<4;y++) gg[g][x][y] = acc[x][y];
  }
  #pragma unroll
  for (int x=0;x<4;x++)
    #pragma unroll
    for (int y=0;y<4;y++){
      int b = bt*64 + tb + x*16;
      int j = jt*64 + tj + y*16;
      float gir = gg[0][x][y] + bih[j];
      float giz = gg[1][x][y] + bih[1024+j];
      float gin = gg[2][x][y] + bih[2048+j];
      float r = sigm(gir + bhh[j]);
      float z = sigm(giz + bhh[1024+j]);
      float nn = tanh_(gin + r*bhh[2048+j]);
      float h = (1.f - z)*nn;
      h_f32[(size_t)j*512 + b] = h;
      h_bf[(size_t)(((b>>4)*32 + (j>>5))*512 + (b&15)*32 + (j&31))] = f2bf(h);
    }
}

__global__ __launch_bounds__(256)
void k_prep_all(const float* __restrict__ dec_in,
                const float* __restrict__ Wih, const float* __restrict__ Whh,
                const float* __restrict__ bih, const float* __restrict__ bhh,
                const float* __restrict__ Wout, const float* __restrict__ bout,
                u16* __restrict__ Wcp, float* __restrict__ cbias,
                u16* __restrict__ WoT,
                float* __restrict__ hf0, u16* __restrict__ hb0,
                unsigned* __restrict__ flags){
  __shared__ float smem[2*64*97];
  int bid = blockIdx.x;
  if (bid < 1536)            prep_wx_body(bid, smem, Wih, Wout, Wcp);
  else if (bid < 4704)       prep_cast_body(bid-1536, Whh, bhh, Wout, Wcp, cbias, WoT);
  else if (bid < 4716)       prep_cx_body(bid-4704, Wih, bih, bout, cbias);
  else                       step0_body(bid-4716, smem, dec_in, Wih, bih, bhh, hf0, hb0, flags);
}

// ---- persistent recurrence, 16 waves (4/SIMD), B-WEIGHTS IN REGISTERS:
// each wave holds its K-half's 48 B-frags (192 VGPRs) for ALL 24 steps.
// Zero steady-state LDS reads for B; LDS only holds the K-split exchange.
__global__ __launch_bounds__(1024, 1)
void k_persist11(const float* __restrict__ hf0, u16* __restrict__ hbase,
                 const u16* __restrict__ Wcp, const float* __restrict__ cbias,
                 unsigned* __restrict__ flags){
  __shared__ f32x4 sRed[8][2][3][64]; // 48 KB: K-split partial exchange
  int b = blockIdx.x, tid = threadIdx.x;
  int lane = tid & 63, w = tid >> 6;          // 16 waves
  int l16 = lane & 15, lk = lane >> 4;
  int kh = w & 1, wr = w >> 1;                // K-half, row-group (0..7)
  int r8 = b & 7;
  int bt = r8 >> 2;                           // batch half (XCDs 0-3 / 4-7)
  int ct = (b >> 3)*4 + (r8 & 3);             // slice [0,128)

  float c0 = cbias[ct*48 +  0 + l16];
  float c1 = cbias[ct*48 + 16 + l16];
  float c2 = cbias[ct*48 + 32 + l16];
  bool hiB = (l16 & 8) != 0;
  int rowA = bt*256 + wr*32;                  // row-group owns 32 batch rows
  int rb0 = rowA >> 4;                        // first A-frag (2 frags: rb0, rb0+1)
  int myFlag = bt*128 + ct;
  const int gk0 = kh*16;                      // this wave's first kit
  const int other = kh ^ 1;
  const bool kh0 = (kh == 0);

  // ---- B weights into registers, once, straight from global (L2-resident).
  // breg[q][nf] = B-frag for kit gk0+q, nf. 48 x short8 = 192 VGPRs.
  const short8* Bg = (const short8*)Wcp + (size_t)ct*6144 + gk0*192 + lane;
  short8 breg[16][3];
  #pragma unroll
  for (int q = 0; q < 16; q++)
    #pragma unroll
    for (int nf = 0; nf < 3; nf++)
      breg[q][nf] = Bg[q*192 + nf*64];
  asm volatile("s_waitcnt vmcnt(0)" ::: "memory");

  // f32 carry for this wave's OWNED m-frag (global frag rb0+kh), 16 rows
  float hold[4];
  if (!hiB){
    int colg = ct*8 + l16;                    // l16 < 8 here
    f32x4 h4 = *(const f32x4*)(hf0 + (size_t)colg*512 + rowA + kh*16 + lk*4);
    hold[0]=h4[0]; hold[1]=h4[1]; hold[2]=h4[2]; hold[3]=h4[3];
  }

  for (int t = 1; t <= 24; ++t){
    const short8* pin8 = (const short8*)(hbase + (size_t)(t-1)*HSZ);
    u16* pout = hbase + (size_t)t*HSZ;
    const short8* Ap = pin8 + (size_t)rb0*2048 + l16*4 + lk;

    short8 ar[4][2];   // [slot][m] — asm-defined VGPRs, un-sinkable
    #define AISSUE(k, s) { \
      aload(ar[s][0], Ap + 0*2048 + (size_t)(k)*64); \
      aload(ar[s][1], Ap + 1*2048 + (size_t)(k)*64); }

    // prologue: this half's kits 0..3 in flight (8 loads)
    AISSUE(gk0+0,0); AISSUE(gk0+1,1); AISSUE(gk0+2,2); AISSUE(gk0+3,3);

    f32x4 acc[2][3];
    #pragma unroll
    for (int m=0;m<2;m++)
      #pragma unroll
      for (int nf=0;nf<3;nf++) acc[m][nf] = f32x4{0.f,0.f,0.f,0.f};

    #pragma unroll
    for (int q = 0; q < 16; q++){
      const int sa = q & 3;
      if (q <= 12)      asm volatile("s_waitcnt vmcnt(6)" ::: "memory");
      else if (q == 13) asm volatile("s_waitcnt vmcnt(4)" ::: "memory");
      else if (q == 14) asm volatile("s_waitcnt vmcnt(2)" ::: "memory");
      else              asm volatile("s_waitcnt vmcnt(0)" ::: "memory");
      __builtin_amdgcn_sched_barrier(0);
      acc[0][0] = __builtin_amdgcn_mfma_f32_16x16x32_bf16(ar[sa][0], breg[q][0], acc[0][0], 0,0,0);
      acc[1][0] = __builtin_amdgcn_mfma_f32_16x16x32_bf16(ar[sa][1], breg[q][0], acc[1][0], 0,0,0);
      acc[0][1] = __builtin_amdgcn_mfma_f32_16x16x32_bf16(ar[sa][0], breg[q][1], acc[0][1], 0,0,0);
      acc[1][1] = __builtin_amdgcn_mfma_f32_16x16x32_bf16(ar[sa][1], breg[q][1], acc[1][1], 0,0,0);
      acc[0][2] = __builtin_amdgcn_mfma_f32_16x16x32_bf16(ar[sa][0], breg[q][2], acc[0][2], 0,0,0);
      acc[1][2] = __builtin_amdgcn_mfma_f32_16x16x32_bf16(ar[sa][1], breg[q][2], acc[1][2], 0,0,0);
      if (q < 12) AISSUE(gk0+q+4, sa);
    }
    #undef AISSUE

    // ---- K-split exchange (STATIC indices; uniform select picks the arm):
    // send the NON-owned frag (frag index rb0+other), keep frag rb0+kh
    #pragma unroll
    for (int nf = 0; nf < 3; nf++)
      sRed[wr][kh][nf][lane] = kh0 ? acc[1][nf] : acc[0][nf];
    __syncthreads();
    f32x4 own[3];
    #pragma unroll
    for (int nf = 0; nf < 3; nf++)
      own[nf] = (kh0 ? acc[0][nf] : acc[1][nf]) + sRed[wr][other][nf][lane];

    // ---- gates for the OWNED frag via lane pair (l, l^8)
    {
      #pragma unroll
      for (int j=0;j<4;j++){
        float g0 = own[0][j] + c0;
        float g1 = own[1][j] + c1;
        float g2 = own[2][j] + c2;
        float v1 = hiB ? g1 : g2;
        float w1 = __shfl_xor(v1, 8, 64);
        float rz = sigm(g0 + w1);
        float w2 = __shfl_xor(rz, 8, 64);
        float v3 = hiB ? (w2 * g2) : 0.f;
        float w3 = __shfl_xor(v3, 8, 64);
        float hnew = 0.f;
        if (!hiB){
          float nn = tanh_(g1 + w3);
          hnew = (1.f - w2)*nn + w2*hold[j];
          hold[j] = hnew;
        }
        float o1 = __shfl_xor(hnew, 1, 64);
        unsigned pk = ((unsigned)f2bf(o1) << 16) | (unsigned)f2bf(hnew);
        unsigned pk2 = __shfl_xor(pk, 2, 64);
        unsigned q2 = __shfl_xor(pk, 4, 64);
        unsigned q3 = __shfl_xor(pk2, 4, 64);
        if (l16 == 0){
          u32x4 vv = {pk, pk2, q2, q3};
          store16_wt((char*)pout + (size_t)(rb0+kh)*32768 + (size_t)(ct>>2)*1024
                                 + (size_t)(lk*4+j)*64 + (size_t)(ct&3)*16, vv);
        }
      }
    }

    // ---- fence-free barrier
    __syncthreads();   // drains every wave's stores (vmcnt 0 before s_barrier)
    if (tid == 0)
      __hip_atomic_store(&flags[myFlag], (unsigned)t,
                         __ATOMIC_RELAXED, __HIP_MEMORY_SCOPE_AGENT);
    if (tid < 128){
      unsigned tgt = (unsigned)t;
      while (__hip_atomic_load(&flags[bt*128 + tid], __ATOMIC_RELAXED,
                               __HIP_MEMORY_SCOPE_AGENT) < tgt)
        __builtin_amdgcn_s_sleep(2);
    }
    __syncthreads();
  }
}

// ---- batched out-projection: pred[b][i][:] = hbuf[i][b,:] @ Wout + bout
__global__ __launch_bounds__(384)
void k_pred(const u16* __restrict__ hbase, const u16* __restrict__ WoT,
            const float* __restrict__ bout, float* __restrict__ pred){
  int blk = blockIdx.x;
  int i = blk >> 5, rbt = blk & 31;       // i in [0,25), row-tile in [0,32)
  int tid = threadIdx.x;
  int lane = tid & 63, bn = tid >> 6;     // wave index = bn in [0,6)
  int l16 = lane & 15, lk = lane >> 4;
  const short8* Aq = (const short8*)(hbase + (size_t)i*HSZ)
                     + (size_t)rbt*2048 + l16*4 + lk;
  const short8* Bq = (const short8*)WoT + (size_t)(bn*16 + l16)*128 + lk;
  f32x4 acc = {0.f,0.f,0.f,0.f};
  #pragma unroll 8
  for (int kit = 0; kit < 32; kit++)
    acc = __builtin_amdgcn_mfma_f32_16x16x32_bf16(Aq[kit*64], Bq[kit*4], acc, 0,0,0);
  int c = bn*16 + l16;
  float bb = bout[c];
  #pragma unroll
  for (int j=0;j<4;j++){
    int row = rbt*16 + lk*4 + j;
    pred[(size_t)row*2400 + (size_t)i*96 + c] = acc[j] + bb;
  }
}

extern "C" void kernel_launch(void* const* d_in, const int* in_sizes, int n_in,
                              void* d_out, int out_size, void* d_ws, size_t ws_size,
                              hipStream_t stream){
  // inputs: 0 enc_in, 1 dec_in, 2..5 enc_* (DEAD CODE), 6 dec_Wih, 7 dec_Whh,
  //         8 dec_bih, 9 dec_bhh, 10 W_out, 11 b_out
  const float* dec_in = (const float*)d_in[1];
  const float* Wih  = (const float*)d_in[6];
  const float* Whh  = (const float*)d_in[7];
  const float* bih  = (const float*)d_in[8];
  const float* bhh  = (const float*)d_in[9];
  const float* Wout = (const float*)d_in[10];
  const float* bout = (const float*)d_in[11];
  float* pred = (float*)d_out;   // [512][25][96] fp32

  char* ws = (char*)d_ws;
  size_t off = 0;
  u16* Wcp = (u16*)(ws + off);   off += (size_t)CTB*48*1024*2;     // 12.58 MB
  u16* WoT = (u16*)(ws + off);   off += (size_t)96*1024*2;
  float* cbias = (float*)(ws + off); off += (size_t)6144*4;
  off = (off + 255) & ~(size_t)255;
  float* hf0 = (float*)(ws + off); off += (size_t)BB*HH*4;   // col-major f32 carry seed
  u16* hbase = (u16*)(ws + off);   off += (size_t)TT*HSZ*2;  // 25 write-once bf16 buffers
  off = (off + 255) & ~(size_t)255;
  unsigned* flags = (unsigned*)(ws + off); off += 1024;

  k_prep_all<<<4844, 256, 0, stream>>>(dec_in, Wih, Whh, bih, bhh, Wout, bout,
                                       Wcp, cbias, WoT, hf0, hbase, flags);

  const float* hf0_c = hf0;
  void* kargs[] = {(void*)&hf0_c, (void*)&hbase, (void*)&Wcp, (void*)&cbias,
                   (void*)&flags};
  hipLaunchCooperativeKernel((const void*)k_persist11, dim3(256), dim3(1024),
                             kargs, 0, stream);

  k_pred<<<800, 384, 0, stream>>>(hbase, WoT, bout, pred);
}

// Round 16
// 633.322 us; speedup vs baseline: 1.6471x; 1.6471x over previous
//
#include <hip/hip_runtime.h>
#include <hip/hip_bf16.h>

typedef __attribute__((ext_vector_type(8))) short short8;
typedef __attribute__((ext_vector_type(4))) float f32x4;
typedef __attribute__((ext_vector_type(4))) unsigned u32x4;
typedef unsigned short u16;

// Problem constants
#define BB 512     // batch
#define HH 1024    // hidden
#define TT 25      // decoder steps
#define CTB 128    // ct slices (each owns 8 hidden cols -> 48 Wc rows)
#define HSZ (BB*HH)   // elements in one h_bf buffer

// h_bf layout (A-frag tiled, per buffer): u16 index of (b, j) =
//   ((b>>4)*32 + (j>>5))*512 + (b&15)*32 + (j&31)

__device__ __forceinline__ float sigm(float x){ return 1.f/(1.f+__expf(-x)); }
__device__ __forceinline__ float tanh_(float x){
  float e = __expf(-2.f*fabsf(x));
  float t = (1.f-e)/(1.f+e);
  return copysignf(t, x);
}
__device__ __forceinline__ u16 f2bf(float x){
  union { float f; unsigned u; } v; v.f = x;
  unsigned r = v.u + 0x7FFFu + ((v.u>>16)&1u);
  return (u16)(r>>16);
}
// 16B write-through store (visible at coherence point after vmcnt drain)
__device__ __forceinline__ void store16_wt(void* p, u32x4 v){
  asm volatile("global_store_dwordx4 %0, %1, off sc0 sc1" :: "v"(p), "v"(v) : "memory");
}
// un-sinkable 16B load into explicit VGPRs (completion via manual s_waitcnt)
__device__ __forceinline__ void aload(short8 &d, const short8* p){
  asm volatile("global_load_dwordx4 %0, %1, off" : "=v"(d) : "v"(p));
}

#if __has_builtin(__builtin_amdgcn_global_load_lds)
#define GLOAD_LDS16(g, l) __builtin_amdgcn_global_load_lds( \
    (const __attribute__((address_space(1))) void*)(g), \
    (__attribute__((address_space(3))) void*)(l), 16, 0, 0)
#define HAVE_GLL 1
#else
#define HAVE_GLL 0
#endif

// Wcp layout: per ct slice (8 hidden cols), 48 rows (r = gate*8 + u, gates:
// 0=gir 1=giz 2=gin 3=ghr 4=ghz 5=ghn), pre-packed in MFMA B-frag order:
// elem idx = ct*49152 + ((kit*3 + nf)*64 + lane)*8 + e
__device__ __forceinline__ size_t wc_idx(int ct, int r, int k){
  int nf = r>>4, rl = r&15, kit = k>>5, k31 = k&31;
  int lane = rl | (((k31>>3)&3)<<4);
  return (size_t)ct*49152 + ((size_t)(kit*3+nf)*64 + (size_t)lane)*8 + (k31&7);
}

// ================= merged prep kernel (one launch) =================
// blocks [0,1536): wx | [1536,4704): cast | [4704,4716): cx | [4716,4844): step0

__device__ void prep_wx_body(int bid, float* smem,
                             const float* __restrict__ Wih,
                             const float* __restrict__ Wout,
                             u16* __restrict__ Wcp){
  float (*sWih)[97] = (float(*)[97])smem;            // 32*97
  float (*sWo)[97]  = (float(*)[97])(smem + 32*97);  // 64*97
  int tid = threadIdx.x;
  int nt = bid % 96, kt = bid / 96;   // n-tile 32, k-tile 64
  for (int i = tid; i < 32*96; i += 256){ int r2=i/96, d=i%96; sWih[r2][d] = Wih[(size_t)(nt*32+r2)*96 + d]; }
  for (int i = tid; i < 64*96; i += 256){ int r2=i/96, d=i%96; sWo[r2][d]  = Wout[(size_t)(kt*64+r2)*96 + d]; }
  __syncthreads();
  int ni = tid & 31, kb = tid >> 5;    // thread owns 8 consecutive k
  float acc[8];
  #pragma unroll
  for (int i=0;i<8;i++) acc[i]=0.f;
  for (int d = 0; d < 96; d++){
    float a = sWih[ni][d];
    #pragma unroll
    for (int i=0;i<8;i++) acc[i] += a * sWo[kb*8 + i][d];
  }
  int n = nt*32 + ni;
  int g = n >> 10, j = n & 1023;
  int ct = j >> 3, u = j & 7, r = g*8 + u;
  size_t base = wc_idx(ct, r, kt*64 + kb*8);
  #pragma unroll
  for (int i=0;i<8;i++) Wcp[base+i] = f2bf(acc[i]);
}

__device__ void prep_cast_body(int bid,
                               const float* __restrict__ Whh, const float* __restrict__ bhh,
                               const float* __restrict__ Wout,
                               u16* __restrict__ Wcp, float* __restrict__ cbias,
                               u16* __restrict__ WoT){
  int tid = threadIdx.x;
  if (bid < 3072){
    int g1 = bid >> 10, j = bid & 1023;
    int ct = j >> 3, u = j & 7, r = (3+g1)*8 + u;
    const float* src = Whh + (size_t)bid*1024;
    if (tid < 128){
      int k0 = tid*8;
      size_t base = wc_idx(ct, r, k0);
      #pragma unroll
      for (int i=0;i<8;i++) Wcp[base+i] = f2bf(src[k0+i]);
    }
    if (!tid) cbias[ct*48 + r] = bhh[bid];
  } else {
    int d = bid - 3072;
    for (int k = tid; k < 1024; k += 256)
      WoT[(size_t)d*1024 + k] = f2bf(Wout[(size_t)k*96 + d]);
  }
}

__device__ void prep_cx_body(int bid,
                             const float* __restrict__ Wih, const float* __restrict__ bih,
                             const float* __restrict__ bout, float* __restrict__ cbias){
  int n = bid*256 + threadIdx.x;
  if (n >= 3072) return;
  float acc = bih[n];
  const float* wrow = Wih + (size_t)n*96;
  for (int d = 0; d < 96; d++) acc += bout[d]*wrow[d];
  int g = n >> 10, j = n & 1023;
  cbias[(j>>3)*48 + g*8 + (j&7)] = acc;
}

__device__ void step0_body(int bid, float* smem,
                           const float* __restrict__ dec_in, const float* __restrict__ Wih,
                           const float* __restrict__ bih, const float* __restrict__ bhh,
                           float* __restrict__ h_f32, u16* __restrict__ h_bf,
                           unsigned* __restrict__ flags){
  if (bid == 0 && threadIdx.x < 256) flags[threadIdx.x] = 0u;
  float (*sP)[97] = (float(*)[97])smem;            // 64*97
  float (*sW)[97] = (float(*)[97])(smem + 64*97);  // 64*97
  int tid = threadIdx.x;
  int bt = bid & 7;
  int jt = bid >> 3;
  for (int i = tid; i < 64*96; i += 256){ int r=i/96, d=i%96; sP[r][d] = dec_in[(size_t)(bt*64+r)*96 + d]; }
  int tb = tid >> 4, tj = tid & 15;
  float gg[3][4][4];
  for (int g = 0; g < 3; g++){
    __syncthreads();
    for (int i = tid; i < 64*96; i += 256){ int r=i/96, d=i%96; sW[r][d] = Wih[((size_t)g*1024 + jt*64 + r)*96 + d]; }
    __syncthreads();
    float acc[4][4];
    #pragma unroll
    for (int x=0;x<4;x++)
      #pragma unroll
      for (int y=0;y<4;y++) acc[x][y]=0.f;
    for (int d = 0; d < 96; d++){
      float a[4], wv[4];
      #pragma unroll
      for (int x=0;x<4;x++) a[x]  = sP[tb + x*16][d];
      #pragma unroll
      for (int y=0;y<4;y++) wv[y] = sW[tj + y*16][d];
      #pragma unroll
      for (int x=0;x<4;x++)
        #pragma unroll
        for (int y=0;y<4;y++) acc[x][y] += a[x]*wv[y];
    }
    #pragma unroll
    for (int x=0;x<4;x++)
      #pragma unroll
      for (int y=0;y<4;y++) gg[g][x][y] = acc[x][y];
  }
  #pragma unroll
  for (int x=0;x<4;x++)
    #pragma unroll
    for (int y=0;y<4;y++){
      int b = bt*64 + tb + x*16;
      int j = jt*64 + tj + y*16;
      float gir = gg[0][x][y] + bih[j];
      float giz = gg[1][x][y] + bih[1024+j];
      float gin = gg[2][x][y] + bih[2048+j];
      float r = sigm(gir + bhh[j]);
      float z = sigm(giz + bhh[1024+j]);
      float nn = tanh_(gin + r*bhh[2048+j]);
      float h = (1.f - z)*nn;
      h_f32[(size_t)j*512 + b] = h;
      h_bf[(size_t)(((b>>4)*32 + (j>>5))*512 + (b&15)*32 + (j&31))] = f2bf(h);
    }
}

__global__ __launch_bounds__(256)
void k_prep_all(const float* __restrict__ dec_in,
                const float* __restrict__ Wih, const float* __restrict__ Whh,
                const float* __restrict__ bih, const float* __restrict__ bhh,
                const float* __restrict__ Wout, const float* __restrict__ bout,
                u16* __restrict__ Wcp, float* __restrict__ cbias,
                u16* __restrict__ WoT,
                float* __restrict__ hf0, u16* __restrict__ hb0,
                unsigned* __restrict__ flags){
  __shared__ float smem[2*64*97];
  int bid = blockIdx.x;
  if (bid < 1536)            prep_wx_body(bid, smem, Wih, Wout, Wcp);
  else if (bid < 4704)       prep_cast_body(bid-1536, Whh, bhh, Wout, Wcp, cbias, WoT);
  else if (bid < 4716)       prep_cx_body(bid-4704, Wih, bih, bout, cbias);
  else                       step0_body(bid-4716, smem, dec_in, Wih, bih, bhh, hf0, hb0, flags);
}

// ---- persistent recurrence, 16 waves (4/SIMD), K-split, PRED FUSED IN SLACK:
// blocks with ct<96 also own one pred tile (16 rows x 96 cols); 12 waves compute
// split-K partials during barrier slack, waves 0-5 reduce+write after the join.
__global__ __launch_bounds__(1024, 1)
void k_persist12(const float* __restrict__ hf0, u16* __restrict__ hbase,
                 const u16* __restrict__ Wcp, const float* __restrict__ cbias,
                 const u16* __restrict__ WoT, const float* __restrict__ bout,
                 float* __restrict__ pred, unsigned* __restrict__ flags){
  __shared__ short8 sB[6144];         // 96 KB: Wc slice, staged ONCE
  __shared__ f32x4 sRed[8][2][3][64]; // 48 KB: K-split partial exchange
  __shared__ f32x4 sPred[6][2][64];   // 12 KB: pred split-K partials
  int b = blockIdx.x, tid = threadIdx.x;
  int lane = tid & 63, w = tid >> 6;          // 16 waves
  int l16 = lane & 15, lk = lane >> 4;
  int kh = w & 1, wr = w >> 1;                // K-half, row-group (0..7)
  int r8 = b & 7;
  int bt = r8 >> 2;                           // batch half (XCDs 0-3 / 4-7)
  int ct = (b >> 3)*4 + (r8 & 3);             // slice [0,128)

  const short8* Wblk = (const short8*)Wcp + (size_t)ct*6144;
#if HAVE_GLL
  #pragma unroll
  for (int it = 0; it < 6; it++){
    int i = it*1024 + tid;
    GLOAD_LDS16(Wblk + i, &sB[i]);
  }
#else
  for (int i = tid; i < 6144; i += 1024) sB[i] = Wblk[i];
#endif

  float c0 = cbias[ct*48 +  0 + l16];
  float c1 = cbias[ct*48 + 16 + l16];
  float c2 = cbias[ct*48 + 32 + l16];
  bool hiB = (l16 & 8) != 0;
  int rowA = bt*256 + wr*32;                  // row-group owns 32 batch rows
  int rb0 = rowA >> 4;                        // first A-frag (2 frags: rb0, rb0+1)
  int myFlag = bt*128 + ct;
  const int gk0 = kh*16;                      // this wave's first kit
  const int other = kh ^ 1;
  const bool kh0 = (kh == 0);
  // pred tile assignment (blocks ct<96): tile rows bt*256+bm*16, cols 0..95
  const bool doPredBlk = (ct < 96);
  const int bm = ct / 6;                      // pred row-tile within half
  const int predFrag = bt*16 + bm;            // A-frag index of pred rows

  // f32 carry for this wave's OWNED m-frag (global frag rb0+kh), 16 rows
  float hold[4];
  if (!hiB){
    int colg = ct*8 + l16;                    // l16 < 8 here
    f32x4 h4 = *(const f32x4*)(hf0 + (size_t)colg*512 + rowA + kh*16 + lk*4);
    hold[0]=h4[0]; hold[1]=h4[1]; hold[2]=h4[2]; hold[3]=h4[3];
  }
  __syncthreads();   // Wc staging complete

  for (int t = 1; t <= 24; ++t){
    const short8* pin8 = (const short8*)(hbase + (size_t)(t-1)*HSZ);
    u16* pout = hbase + (size_t)t*HSZ;
    const short8* Ap = pin8 + (size_t)rb0*2048 + l16*4 + lk;

    short8 ar[4][2];   // [slot][m] — asm-defined VGPRs, un-sinkable
    #define AISSUE(k, s) { \
      aload(ar[s][0], Ap + 0*2048 + (size_t)(k)*64); \
      aload(ar[s][1], Ap + 1*2048 + (size_t)(k)*64); }

    // prologue: this half's kits 0..3 in flight (8 loads)
    AISSUE(gk0+0,0); AISSUE(gk0+1,1); AISSUE(gk0+2,2); AISSUE(gk0+3,3);

    short8 brw[2][3];
    #pragma unroll
    for (int nf = 0; nf < 3; nf++) brw[0][nf] = sB[gk0*192 + nf*64 + lane];

    f32x4 acc[2][3];
    #pragma unroll
    for (int m=0;m<2;m++)
      #pragma unroll
      for (int nf=0;nf<3;nf++) acc[m][nf] = f32x4{0.f,0.f,0.f,0.f};

    #pragma unroll
    for (int q = 0; q < 16; q++){
      const int cur = q & 1, nxt = cur ^ 1, sa = q & 3;
      if (q <= 12)      asm volatile("s_waitcnt vmcnt(6)" ::: "memory");
      else if (q == 13) asm volatile("s_waitcnt vmcnt(4)" ::: "memory");
      else if (q == 14) asm volatile("s_waitcnt vmcnt(2)" ::: "memory");
      else              asm volatile("s_waitcnt vmcnt(0)" ::: "memory");
      __builtin_amdgcn_sched_barrier(0);
      if (q < 15){
        #pragma unroll
        for (int nf = 0; nf < 3; nf++) brw[nxt][nf] = sB[(gk0+q+1)*192 + nf*64 + lane];
      }
      acc[0][0] = __builtin_amdgcn_mfma_f32_16x16x32_bf16(ar[sa][0], brw[cur][0], acc[0][0], 0,0,0);
      acc[1][0] = __builtin_amdgcn_mfma_f32_16x16x32_bf16(ar[sa][1], brw[cur][0], acc[1][0], 0,0,0);
      acc[0][1] = __builtin_amdgcn_mfma_f32_16x16x32_bf16(ar[sa][0], brw[cur][1], acc[0][1], 0,0,0);
      acc[1][1] = __builtin_amdgcn_mfma_f32_16x16x32_bf16(ar[sa][1], brw[cur][1], acc[1][1], 0,0,0);
      acc[0][2] = __builtin_amdgcn_mfma_f32_16x16x32_bf16(ar[sa][0], brw[cur][2], acc[0][2], 0,0,0);
      acc[1][2] = __builtin_amdgcn_mfma_f32_16x16x32_bf16(ar[sa][1], brw[cur][2], acc[1][2], 0,0,0);
      if (q < 12) AISSUE(gk0+q+4, sa);
    }
    #undef AISSUE

    // ---- K-split exchange (STATIC indices; uniform select picks the arm)
    #pragma unroll
    for (int nf = 0; nf < 3; nf++)
      sRed[wr][kh][nf][lane] = kh0 ? acc[1][nf] : acc[0][nf];
    __syncthreads();
    f32x4 own[3];
    #pragma unroll
    for (int nf = 0; nf < 3; nf++)
      own[nf] = (kh0 ? acc[0][nf] : acc[1][nf]) + sRed[wr][other][nf][lane];

    // ---- gates for the OWNED frag via lane pair (l, l^8)
    {
      #pragma unroll
      for (int j=0;j<4;j++){
        float g0 = own[0][j] + c0;
        float g1 = own[1][j] + c1;
        float g2 = own[2][j] + c2;
        float v1 = hiB ? g1 : g2;
        float w1 = __shfl_xor(v1, 8, 64);
        float rz = sigm(g0 + w1);
        float w2 = __shfl_xor(rz, 8, 64);
        float v3 = hiB ? (w2 * g2) : 0.f;
        float w3 = __shfl_xor(v3, 8, 64);
        float hnew = 0.f;
        if (!hiB){
          float nn = tanh_(g1 + w3);
          hnew = (1.f - w2)*nn + w2*hold[j];
          hold[j] = hnew;
        }
        float o1 = __shfl_xor(hnew, 1, 64);
        unsigned pk = ((unsigned)f2bf(o1) << 16) | (unsigned)f2bf(hnew);
        unsigned pk2 = __shfl_xor(pk, 2, 64);
        unsigned q2 = __shfl_xor(pk, 4, 64);
        unsigned q3 = __shfl_xor(pk2, 4, 64);
        if (l16 == 0){
          u32x4 vv = {pk, pk2, q2, q3};
          store16_wt((char*)pout + (size_t)(rb0+kh)*32768 + (size_t)(ct>>2)*1024
                                 + (size_t)(lk*4+j)*64 + (size_t)(ct&3)*16, vv);
        }
      }
    }

    // ---- barrier: release, pred partials in the slack, poll, join
    __syncthreads();   // drains every wave's stores (vmcnt 0 before s_barrier)
    if (tid == 0)
      __hip_atomic_store(&flags[myFlag], (unsigned)t,
                         __ATOMIC_RELAXED, __HIP_MEMORY_SCOPE_AGENT);
    if (doPredBlk && w >= 2 && w < 14){
      int pw = w - 2, pbn = pw % 6, pk2 = pw / 6;   // bn 0..5, K-half 0..1
      const short8* Aq = pin8 + (size_t)predFrag*2048 + l16*4 + lk;
      const short8* Bq = (const short8*)WoT + (size_t)(pbn*16 + l16)*128 + lk;
      f32x4 accp = {0.f,0.f,0.f,0.f};
      #pragma unroll 4
      for (int q2 = 0; q2 < 16; q2++){
        int kit = pk2*16 + q2;
        accp = __builtin_amdgcn_mfma_f32_16x16x32_bf16(Aq[(size_t)kit*64], Bq[kit*4], accp, 0,0,0);
      }
      sPred[pbn][pk2][lane] = accp;
    }
    if (tid < 128){
      unsigned tgt = (unsigned)t;
      while (__hip_atomic_load(&flags[bt*128 + tid], __ATOMIC_RELAXED,
                               __HIP_MEMORY_SCOPE_AGENT) < tgt)
        __builtin_amdgcn_s_sleep(2);
    }
    __syncthreads();   // join; also orders sPred writes before reads below
    if (doPredBlk && w < 6){
      f32x4 s = sPred[w][0][lane] + sPred[w][1][lane];
      int c = w*16 + l16;
      float bb = bout[c];
      #pragma unroll
      for (int j=0;j<4;j++){
        int row = bt*256 + bm*16 + lk*4 + j;
        pred[(size_t)row*2400 + (size_t)(t-1)*96 + c] = s[j] + bb;
      }
    }
  }

  // ---- epilogue: pred[24] from hbase[24] (all flags at 24, writes visible)
  if (doPredBlk){
    const short8* pin8 = (const short8*)(hbase + (size_t)24*HSZ);
    if (w >= 2 && w < 14){
      int pw = w - 2, pbn = pw % 6, pk2 = pw / 6;
      const short8* Aq = pin8 + (size_t)predFrag*2048 + l16*4 + lk;
      const short8* Bq = (const short8*)WoT + (size_t)(pbn*16 + l16)*128 + lk;
      f32x4 accp = {0.f,0.f,0.f,0.f};
      #pragma unroll 4
      for (int q2 = 0; q2 < 16; q2++){
        int kit = pk2*16 + q2;
        accp = __builtin_amdgcn_mfma_f32_16x16x32_bf16(Aq[(size_t)kit*64], Bq[kit*4], accp, 0,0,0);
      }
      sPred[pbn][pk2][lane] = accp;
    }
    __syncthreads();
    if (w < 6){
      f32x4 s = sPred[w][0][lane] + sPred[w][1][lane];
      int c = w*16 + l16;
      float bb = bout[c];
      #pragma unroll
      for (int j=0;j<4;j++){
        int row = bt*256 + bm*16 + lk*4 + j;
        pred[(size_t)row*2400 + (size_t)24*96 + c] = s[j] + bb;
      }
    }
  }
}

extern "C" void kernel_launch(void* const* d_in, const int* in_sizes, int n_in,
                              void* d_out, int out_size, void* d_ws, size_t ws_size,
                              hipStream_t stream){
  // inputs: 0 enc_in, 1 dec_in, 2..5 enc_* (DEAD CODE), 6 dec_Wih, 7 dec_Whh,
  //         8 dec_bih, 9 dec_bhh, 10 W_out, 11 b_out
  const float* dec_in = (const float*)d_in[1];
  const float* Wih  = (const float*)d_in[6];
  const float* Whh  = (const float*)d_in[7];
  const float* bih  = (const float*)d_in[8];
  const float* bhh  = (const float*)d_in[9];
  const float* Wout = (const float*)d_in[10];
  const float* bout = (const float*)d_in[11];
  float* pred = (float*)d_out;   // [512][25][96] fp32

  char* ws = (char*)d_ws;
  size_t off = 0;
  u16* Wcp = (u16*)(ws + off);   off += (size_t)CTB*48*1024*2;     // 12.58 MB
  u16* WoT = (u16*)(ws + off);   off += (size_t)96*1024*2;
  float* cbias = (float*)(ws + off); off += (size_t)6144*4;
  off = (off + 255) & ~(size_t)255;
  float* hf0 = (float*)(ws + off); off += (size_t)BB*HH*4;   // col-major f32 carry seed
  u16* hbase = (u16*)(ws + off);   off += (size_t)TT*HSZ*2;  // 25 write-once bf16 buffers
  off = (off + 255) & ~(size_t)255;
  unsigned* flags = (unsigned*)(ws + off); off += 1024;

  k_prep_all<<<4844, 256, 0, stream>>>(dec_in, Wih, Whh, bih, bhh, Wout, bout,
                                       Wcp, cbias, WoT, hf0, hbase, flags);

  const float* hf0_c = hf0;
  const u16* WoT_c = WoT;
  void* kargs[] = {(void*)&hf0_c, (void*)&hbase, (void*)&Wcp, (void*)&cbias,
                   (void*)&WoT_c, (void*)&bout, (void*)&pred, (void*)&flags};
  hipLaunchCooperativeKernel((const void*)k_persist12, dim3(256), dim3(1024),
                             kargs, 0, stream);
}

// Round 17
// 453.481 us; speedup vs baseline: 2.3003x; 1.3966x over previous
//
#include <hip/hip_runtime.h>
#include <hip/hip_bf16.h>

typedef __attribute__((ext_vector_type(8))) short short8;
typedef __attribute__((ext_vector_type(4))) float f32x4;
typedef __attribute__((ext_vector_type(4))) unsigned u32x4;
typedef unsigned short u16;

// Problem constants
#define BB 512     // batch
#define HH 1024    // hidden
#define TT 25      // decoder steps
#define CTB 128    // ct slices (each owns 8 hidden cols -> 48 Wc rows)
#define HSZ (BB*HH)   // elements in one h_bf buffer

// h_bf layout (A-frag tiled, per buffer): u16 index of (b, j) =
//   ((b>>4)*32 + (j>>5))*512 + (b&15)*32 + (j&31)
// -> one MFMA A-frag (16 rows x 32 cols) is a contiguous aligned 1 KB block.

__device__ __forceinline__ float sigm(float x){ return 1.f/(1.f+__expf(-x)); }
__device__ __forceinline__ float tanh_(float x){
  float e = __expf(-2.f*fabsf(x));
  float t = (1.f-e)/(1.f+e);
  return copysignf(t, x);
}
__device__ __forceinline__ u16 f2bf(float x){
  union { float f; unsigned u; } v; v.f = x;
  unsigned r = v.u + 0x7FFFu + ((v.u>>16)&1u);
  return (u16)(r>>16);
}
// 16B write-through store (visible at coherence point after vmcnt drain)
__device__ __forceinline__ void store16_wt(void* p, u32x4 v){
  asm volatile("global_store_dwordx4 %0, %1, off sc0 sc1" :: "v"(p), "v"(v) : "memory");
}
// un-sinkable 16B load into explicit VGPRs (completion via manual s_waitcnt)
__device__ __forceinline__ void aload(short8 &d, const short8* p){
  asm volatile("global_load_dwordx4 %0, %1, off" : "=v"(d) : "v"(p));
}

#if __has_builtin(__builtin_amdgcn_global_load_lds)
#define GLOAD_LDS16(g, l) __builtin_amdgcn_global_load_lds( \
    (const __attribute__((address_space(1))) void*)(g), \
    (__attribute__((address_space(3))) void*)(l), 16, 0, 0)
#define HAVE_GLL 1
#else
#define HAVE_GLL 0
#endif

// Wcp layout: per ct slice (8 hidden cols), 48 rows (r = gate*8 + u, gates:
// 0=gir 1=giz 2=gin 3=ghr 4=ghz 5=ghn), pre-packed in MFMA B-frag order:
// elem idx = ct*49152 + ((kit*3 + nf)*64 + lane)*8 + e
__device__ __forceinline__ size_t wc_idx(int ct, int r, int k){
  int nf = r>>4, rl = r&15, kit = k>>5, k31 = k&31;
  int lane = rl | (((k31>>3)&3)<<4);
  return (size_t)ct*49152 + ((size_t)(kit*3+nf)*64 + (size_t)lane)*8 + (k31&7);
}

// ================= merged prep kernel (one launch) =================
// blocks [0,1536): wx | [1536,4704): cast | [4704,4716): cx | [4716,4844): step0

__device__ void prep_wx_body(int bid, float* smem,
                             const float* __restrict__ Wih,
                             const float* __restrict__ Wout,
                             u16* __restrict__ Wcp){
  float (*sWih)[97] = (float(*)[97])smem;            // 32*97
  float (*sWo)[97]  = (float(*)[97])(smem + 32*97);  // 64*97
  int tid = threadIdx.x;
  int nt = bid % 96, kt = bid / 96;   // n-tile 32, k-tile 64
  for (int i = tid; i < 32*96; i += 256){ int r2=i/96, d=i%96; sWih[r2][d] = Wih[(size_t)(nt*32+r2)*96 + d]; }
  for (int i = tid; i < 64*96; i += 256){ int r2=i/96, d=i%96; sWo[r2][d]  = Wout[(size_t)(kt*64+r2)*96 + d]; }
  __syncthreads();
  int ni = tid & 31, kb = tid >> 5;    // thread owns 8 consecutive k
  float acc[8];
  #pragma unroll
  for (int i=0;i<8;i++) acc[i]=0.f;
  for (int d = 0; d < 96; d++){
    float a = sWih[ni][d];
    #pragma unroll
    for (int i=0;i<8;i++) acc[i] += a * sWo[kb*8 + i][d];
  }
  int n = nt*32 + ni;
  int g = n >> 10, j = n & 1023;
  int ct = j >> 3, u = j & 7, r = g*8 + u;
  size_t base = wc_idx(ct, r, kt*64 + kb*8);
  #pragma unroll
  for (int i=0;i<8;i++) Wcp[base+i] = f2bf(acc[i]);
}

__device__ void prep_cast_body(int bid,
                               const float* __restrict__ Whh, const float* __restrict__ bhh,
                               const float* __restrict__ Wout,
                               u16* __restrict__ Wcp, float* __restrict__ cbias,
                               u16* __restrict__ WoT){
  int tid = threadIdx.x;
  if (bid < 3072){
    int g1 = bid >> 10, j = bid & 1023;
    int ct = j >> 3, u = j & 7, r = (3+g1)*8 + u;
    const float* src = Whh + (size_t)bid*1024;
    if (tid < 128){
      int k0 = tid*8;
      size_t base = wc_idx(ct, r, k0);
      #pragma unroll
      for (int i=0;i<8;i++) Wcp[base+i] = f2bf(src[k0+i]);
    }
    if (!tid) cbias[ct*48 + r] = bhh[bid];
  } else {
    int d = bid - 3072;
    for (int k = tid; k < 1024; k += 256)
      WoT[(size_t)d*1024 + k] = f2bf(Wout[(size_t)k*96 + d]);
  }
}

__device__ void prep_cx_body(int bid,
                             const float* __restrict__ Wih, const float* __restrict__ bih,
                             const float* __restrict__ bout, float* __restrict__ cbias){
  int n = bid*256 + threadIdx.x;
  if (n >= 3072) return;
  float acc = bih[n];
  const float* wrow = Wih + (size_t)n*96;
  for (int d = 0; d < 96; d++) acc += bout[d]*wrow[d];
  int g = n >> 10, j = n & 1023;
  cbias[(j>>3)*48 + g*8 + (j&7)] = acc;
}

__device__ void step0_body(int bid, float* smem,
                           const float* __restrict__ dec_in, const float* __restrict__ Wih,
                           const float* __restrict__ bih, const float* __restrict__ bhh,
                           float* __restrict__ h_f32, u16* __restrict__ h_bf,
                           unsigned* __restrict__ flags){
  if (bid == 0 && threadIdx.x < 256) flags[threadIdx.x] = 0u;
  float (*sP)[97] = (float(*)[97])smem;            // 64*97
  float (*sW)[97] = (float(*)[97])(smem + 64*97);  // 64*97
  int tid = threadIdx.x;
  int bt = bid & 7;
  int jt = bid >> 3;
  for (int i = tid; i < 64*96; i += 256){ int r=i/96, d=i%96; sP[r][d] = dec_in[(size_t)(bt*64+r)*96 + d]; }
  int tb = tid >> 4, tj = tid & 15;
  float gg[3][4][4];
  for (int g = 0; g < 3; g++){
    __syncthreads();
    for (int i = tid; i < 64*96; i += 256){ int r=i/96, d=i%96; sW[r][d] = Wih[((size_t)g*1024 + jt*64 + r)*96 + d]; }
    __syncthreads();
    float acc[4][4];
    #pragma unroll
    for (int x=0;x<4;x++)
      #pragma unroll
      for (int y=0;y<4;y++) acc[x][y]=0.f;
    for (int d = 0; d < 96; d++){
      float a[4], wv[4];
      #pragma unroll
      for (int x=0;x<4;x++) a[x]  = sP[tb + x*16][d];
      #pragma unroll
      for (int y=0;y<4;y++) wv[y] = sW[tj + y*16][d];
      #pragma unroll
      for (int x=0;x<4;x++)
        #pragma unroll
        for (int y=0;y<4;y++) acc[x][y] += a[x]*wv[y];
    }
    #pragma unroll
    for (int x=0;x<4;x++)
      #pragma unroll
      for (int y=0;y<4;y++) gg[g][x][y] = acc[x][y];
  }
  #pragma unroll
  for (int x=0;x<4;x++)
    #pragma unroll
    for (int y=0;y<4;y++){
      int b = bt*64 + tb + x*16;
      int j = jt*64 + tj + y*16;
      float gir = gg[0][x][y] + bih[j];
      float giz = gg[1][x][y] + bih[1024+j];
      float gin = gg[2][x][y] + bih[2048+j];
      float r = sigm(gir + bhh[j]);
      float z = sigm(giz + bhh[1024+j]);
      float nn = tanh_(gin + r*bhh[2048+j]);
      float h = (1.f - z)*nn;
      h_f32[(size_t)j*512 + b] = h;
      h_bf[(size_t)(((b>>4)*32 + (j>>5))*512 + (b&15)*32 + (j&31))] = f2bf(h);
    }
}

__global__ __launch_bounds__(256)
void k_prep_all(const float* __restrict__ dec_in,
                const float* __restrict__ Wih, const float* __restrict__ Whh,
                const float* __restrict__ bih, const float* __restrict__ bhh,
                const float* __restrict__ Wout, const float* __restrict__ bout,
                u16* __restrict__ Wcp, float* __restrict__ cbias,
                u16* __restrict__ WoT,
                float* __restrict__ hf0, u16* __restrict__ hb0,
                unsigned* __restrict__ flags){
  __shared__ float smem[2*64*97];
  int bid = blockIdx.x;
  if (bid < 1536)            prep_wx_body(bid, smem, Wih, Wout, Wcp);
  else if (bid < 4704)       prep_cast_body(bid-1536, Whh, bhh, Wout, Wcp, cbias, WoT);
  else if (bid < 4716)       prep_cx_body(bid-4704, Wih, bih, bout, cbias);
  else                       step0_body(bid-4716, smem, dec_in, Wih, bih, bhh, hf0, hb0, flags);
}

// ---- persistent recurrence, 16 waves (4/SIMD): 8 row-groups (32 rows) x 2 K-halves.
// Each wave: 2 m-frags over its 16 kits; owns frag (rb0+kh) after exchange.
// Static acc indexing throughout (rule #20). A in reg-ring (asm loads, vmcnt(6)).
__global__ __launch_bounds__(1024, 1)
void k_persist10(const float* __restrict__ hf0, u16* __restrict__ hbase,
                 const u16* __restrict__ Wcp, const float* __restrict__ cbias,
                 unsigned* __restrict__ flags){
  __shared__ short8 sB[6144];         // 96 KB: Wc slice, staged ONCE
  __shared__ f32x4 sRed[8][2][3][64]; // 48 KB: K-split partial exchange
  int b = blockIdx.x, tid = threadIdx.x;
  int lane = tid & 63, w = tid >> 6;          // 16 waves
  int l16 = lane & 15, lk = lane >> 4;
  int kh = w & 1, wr = w >> 1;                // K-half, row-group (0..7)
  int r8 = b & 7;
  int bt = r8 >> 2;                           // batch half (XCDs 0-3 / 4-7)
  int ct = (b >> 3)*4 + (r8 & 3);             // slice [0,128)

  const short8* Wblk = (const short8*)Wcp + (size_t)ct*6144;
#if HAVE_GLL
  #pragma unroll
  for (int it = 0; it < 6; it++){
    int i = it*1024 + tid;
    GLOAD_LDS16(Wblk + i, &sB[i]);
  }
#else
  for (int i = tid; i < 6144; i += 1024) sB[i] = Wblk[i];
#endif

  float c0 = cbias[ct*48 +  0 + l16];
  float c1 = cbias[ct*48 + 16 + l16];
  float c2 = cbias[ct*48 + 32 + l16];
  bool hiB = (l16 & 8) != 0;
  int rowA = bt*256 + wr*32;                  // row-group owns 32 batch rows
  int rb0 = rowA >> 4;                        // first A-frag (2 frags: rb0, rb0+1)
  int myFlag = bt*128 + ct;
  const int gk0 = kh*16;                      // this wave's first kit
  const int other = kh ^ 1;
  const bool kh0 = (kh == 0);

  // f32 carry for this wave's OWNED m-frag (global frag rb0+kh), 16 rows
  float hold[4];
  if (!hiB){
    int colg = ct*8 + l16;                    // l16 < 8 here
    f32x4 h4 = *(const f32x4*)(hf0 + (size_t)colg*512 + rowA + kh*16 + lk*4);
    hold[0]=h4[0]; hold[1]=h4[1]; hold[2]=h4[2]; hold[3]=h4[3];
  }
  __syncthreads();   // Wc staging complete

  for (int t = 1; t <= 24; ++t){
    const short8* pin8 = (const short8*)(hbase + (size_t)(t-1)*HSZ);
    u16* pout = hbase + (size_t)t*HSZ;
    const short8* Ap = pin8 + (size_t)rb0*2048 + l16*4 + lk;

    short8 ar[4][2];   // [slot][m] — asm-defined VGPRs, un-sinkable
    #define AISSUE(k, s) { \
      aload(ar[s][0], Ap + 0*2048 + (size_t)(k)*64); \
      aload(ar[s][1], Ap + 1*2048 + (size_t)(k)*64); }

    // prologue: this half's kits 0..3 in flight (8 loads)
    AISSUE(gk0+0,0); AISSUE(gk0+1,1); AISSUE(gk0+2,2); AISSUE(gk0+3,3);

    short8 brw[2][3];
    #pragma unroll
    for (int nf = 0; nf < 3; nf++) brw[0][nf] = sB[gk0*192 + nf*64 + lane];

    f32x4 acc[2][3];
    #pragma unroll
    for (int m=0;m<2;m++)
      #pragma unroll
      for (int nf=0;nf<3;nf++) acc[m][nf] = f32x4{0.f,0.f,0.f,0.f};

    #pragma unroll
    for (int q = 0; q < 16; q++){
      const int cur = q & 1, nxt = cur ^ 1, sa = q & 3;
      if (q <= 12)      asm volatile("s_waitcnt vmcnt(6)" ::: "memory");
      else if (q == 13) asm volatile("s_waitcnt vmcnt(4)" ::: "memory");
      else if (q == 14) asm volatile("s_waitcnt vmcnt(2)" ::: "memory");
      else              asm volatile("s_waitcnt vmcnt(0)" ::: "memory");
      __builtin_amdgcn_sched_barrier(0);
      if (q < 15){
        #pragma unroll
        for (int nf = 0; nf < 3; nf++) brw[nxt][nf] = sB[(gk0+q+1)*192 + nf*64 + lane];
      }
      acc[0][0] = __builtin_amdgcn_mfma_f32_16x16x32_bf16(ar[sa][0], brw[cur][0], acc[0][0], 0,0,0);
      acc[1][0] = __builtin_amdgcn_mfma_f32_16x16x32_bf16(ar[sa][1], brw[cur][0], acc[1][0], 0,0,0);
      acc[0][1] = __builtin_amdgcn_mfma_f32_16x16x32_bf16(ar[sa][0], brw[cur][1], acc[0][1], 0,0,0);
      acc[1][1] = __builtin_amdgcn_mfma_f32_16x16x32_bf16(ar[sa][1], brw[cur][1], acc[1][1], 0,0,0);
      acc[0][2] = __builtin_amdgcn_mfma_f32_16x16x32_bf16(ar[sa][0], brw[cur][2], acc[0][2], 0,0,0);
      acc[1][2] = __builtin_amdgcn_mfma_f32_16x16x32_bf16(ar[sa][1], brw[cur][2], acc[1][2], 0,0,0);
      if (q < 12) AISSUE(gk0+q+4, sa);
    }
    #undef AISSUE

    // ---- K-split exchange (STATIC indices; uniform select picks the arm):
    // send the NON-owned frag (frag index rb0+other), keep frag rb0+kh
    #pragma unroll
    for (int nf = 0; nf < 3; nf++)
      sRed[wr][kh][nf][lane] = kh0 ? acc[1][nf] : acc[0][nf];
    __syncthreads();
    f32x4 own[3];
    #pragma unroll
    for (int nf = 0; nf < 3; nf++)
      own[nf] = (kh0 ? acc[0][nf] : acc[1][nf]) + sRed[wr][other][nf][lane];

    // ---- gates for the OWNED frag via lane pair (l, l^8)
    {
      #pragma unroll
      for (int j=0;j<4;j++){
        float g0 = own[0][j] + c0;
        float g1 = own[1][j] + c1;
        float g2 = own[2][j] + c2;
        float v1 = hiB ? g1 : g2;
        float w1 = __shfl_xor(v1, 8, 64);
        float rz = sigm(g0 + w1);
        float w2 = __shfl_xor(rz, 8, 64);
        float v3 = hiB ? (w2 * g2) : 0.f;
        float w3 = __shfl_xor(v3, 8, 64);
        float hnew = 0.f;
        if (!hiB){
          float nn = tanh_(g1 + w3);
          hnew = (1.f - w2)*nn + w2*hold[j];
          hold[j] = hnew;
        }
        float o1 = __shfl_xor(hnew, 1, 64);
        unsigned pk = ((unsigned)f2bf(o1) << 16) | (unsigned)f2bf(hnew);
        unsigned pk2 = __shfl_xor(pk, 2, 64);
        unsigned q2 = __shfl_xor(pk, 4, 64);
        unsigned q3 = __shfl_xor(pk2, 4, 64);
        if (l16 == 0){
          u32x4 vv = {pk, pk2, q2, q3};
          store16_wt((char*)pout + (size_t)(rb0+kh)*32768 + (size_t)(ct>>2)*1024
                                 + (size_t)(lk*4+j)*64 + (size_t)(ct&3)*16, vv);
        }
      }
    }

    // ---- fence-free barrier
    __syncthreads();   // drains every wave's stores (vmcnt 0 before s_barrier)
    if (tid == 0)
      __hip_atomic_store(&flags[myFlag], (unsigned)t,
                         __ATOMIC_RELAXED, __HIP_MEMORY_SCOPE_AGENT);
    if (tid < 128){
      unsigned tgt = (unsigned)t;
      while (__hip_atomic_load(&flags[bt*128 + tid], __ATOMIC_RELAXED,
                               __HIP_MEMORY_SCOPE_AGENT) < tgt)
        __builtin_amdgcn_s_sleep(2);
    }
    __syncthreads();
  }
}

// ---- batched out-projection: pred[b][i][:] = hbuf[i][b,:] @ Wout + bout
__global__ __launch_bounds__(384)
void k_pred(const u16* __restrict__ hbase, const u16* __restrict__ WoT,
            const float* __restrict__ bout, float* __restrict__ pred){
  int blk = blockIdx.x;
  int i = blk >> 5, rbt = blk & 31;       // i in [0,25), row-tile in [0,32)
  int tid = threadIdx.x;
  int lane = tid & 63, bn = tid >> 6;     // wave index = bn in [0,6)
  int l16 = lane & 15, lk = lane >> 4;
  const short8* Aq = (const short8*)(hbase + (size_t)i*HSZ)
                     + (size_t)rbt*2048 + l16*4 + lk;
  const short8* Bq = (const short8*)WoT + (size_t)(bn*16 + l16)*128 + lk;
  f32x4 acc = {0.f,0.f,0.f,0.f};
  #pragma unroll 8
  for (int kit = 0; kit < 32; kit++)
    acc = __builtin_amdgcn_mfma_f32_16x16x32_bf16(Aq[kit*64], Bq[kit*4], acc, 0,0,0);
  int c = bn*16 + l16;
  float bb = bout[c];
  #pragma unroll
  for (int j=0;j<4;j++){
    int row = rbt*16 + lk*4 + j;
    pred[(size_t)row*2400 + (size_t)i*96 + c] = acc[j] + bb;
  }
}

extern "C" void kernel_launch(void* const* d_in, const int* in_sizes, int n_in,
                              void* d_out, int out_size, void* d_ws, size_t ws_size,
                              hipStream_t stream){
  // inputs: 0 enc_in, 1 dec_in, 2..5 enc_* (DEAD CODE), 6 dec_Wih, 7 dec_Whh,
  //         8 dec_bih, 9 dec_bhh, 10 W_out, 11 b_out
  const float* dec_in = (const float*)d_in[1];
  const float* Wih  = (const float*)d_in[6];
  const float* Whh  = (const float*)d_in[7];
  const float* bih  = (const float*)d_in[8];
  const float* bhh  = (const float*)d_in[9];
  const float* Wout = (const float*)d_in[10];
  const float* bout = (const float*)d_in[11];
  float* pred = (float*)d_out;   // [512][25][96] fp32

  char* ws = (char*)d_ws;
  size_t off = 0;
  u16* Wcp = (u16*)(ws + off);   off += (size_t)CTB*48*1024*2;     // 12.58 MB
  u16* WoT = (u16*)(ws + off);   off += (size_t)96*1024*2;
  float* cbias = (float*)(ws + off); off += (size_t)6144*4;
  off = (off + 255) & ~(size_t)255;
  float* hf0 = (float*)(ws + off); off += (size_t)BB*HH*4;   // col-major f32 carry seed
  u16* hbase = (u16*)(ws + off);   off += (size_t)TT*HSZ*2;  // 25 write-once bf16 buffers
  off = (off + 255) & ~(size_t)255;
  unsigned* flags = (unsigned*)(ws + off); off += 1024;

  k_prep_all<<<4844, 256, 0, stream>>>(dec_in, Wih, Whh, bih, bhh, Wout, bout,
                                       Wcp, cbias, WoT, hf0, hbase, flags);

  const float* hf0_c = hf0;
  void* kargs[] = {(void*)&hf0_c, (void*)&hbase, (void*)&Wcp, (void*)&cbias,
                   (void*)&flags};
  hipLaunchCooperativeKernel((const void*)k_persist10, dim3(256), dim3(1024),
                             kargs, 0, stream);

  k_pred<<<800, 384, 0, stream>>>(hbase, WoT, bout, pred);
}